// Round 1
// baseline (271.536 us; speedup 1.0000x reference)
//
#include <hip/hip_runtime.h>

// ts_cov: x[B=256, T=512, F=32] fp32 -> cov[B, S=508, C=496] fp32
// cov[b,s,c(i,j)] = mean_{t in [s,s+5)} x_i x_j - mean(x_i) mean(x_j), pairs i<j row-major.
//
// Write-BW-bound (~258 MB out; floor ~45 us at fill-demonstrated 6.16 TB/s).
// v2: 1 pair per lane, 512 threads/block (496 active), scalar stores streamed
// inside the sliding-window loop. Rationale vs v1 (4 pairs + covreg + float4
// burst): covreg[4][16] cost 64 VGPRs -> ~2-3 waves/SIMD and stores bunched at
// block end; write path drained between bursts. Now ~80 VGPRs -> ~6 waves/SIMD,
// ~24 waves/CU, and each wave emits a 256 B contiguous line-aligned store per
// window, continuously. Per-element arithmetic is identical to v1 (same absmax).

#define T_DIM 512
#define F_DIM 32
#define B_DIM 256
#define WIN 5
#define S_DIM (T_DIM - WIN + 1)          // 508
#define C_DIM (F_DIM * (F_DIM - 1) / 2)  // 496
#define NS 16                            // windows per block
#define NROW (NS + WIN - 1)              // 20 x-rows staged per block

__global__ __launch_bounds__(512) void ts_cov_kernel(const float* __restrict__ x,
                                                     float* __restrict__ out) {
    __shared__ float xt[F_DIM * NROW];   // transposed: xt[f*NROW + t], 2560 B

    const int b   = blockIdx.y;
    const int s0  = blockIdx.x * NS;     // 0,16,...,496
    const int tid = threadIdx.x;

    // ---- Stage x[b, s0 : s0+NROW, :] into LDS, transposed (160 float4s) ----
    const float4* xsrc = (const float4*)(x + ((size_t)b * T_DIM + s0) * F_DIM);
    const int nrow_avail = min(NROW, T_DIM - s0);          // 20, or 16 for last tile
    if (tid < NROW * F_DIM / 4) {
        const int t  = tid >> 3;                           // row within tile
        const int f4 = tid & 7;                            // float4 within row
        float4 v = (t < nrow_avail) ? xsrc[tid] : make_float4(0.f, 0.f, 0.f, 0.f);
        xt[(4 * f4 + 0) * NROW + t] = v.x;
        xt[(4 * f4 + 1) * NROW + t] = v.y;
        xt[(4 * f4 + 2) * NROW + t] = v.z;
        xt[(4 * f4 + 3) * NROW + t] = v.w;
    }
    __syncthreads();

    if (tid >= C_DIM) return;            // 496 active lanes, one pair each

    const int nw = min(NS, S_DIM - s0);  // 16, or 12 for last tile

    // Decode pair (i, j) for c = tid. Lanes are consecutive in c, so a wave's
    // stores cover 64 consecutive floats (256 B, full 64B lines).
    int i = 0, cc = tid;
    while (cc >= F_DIM - 1 - i) { cc -= F_DIM - 1 - i; ++i; }
    const int j = i + 1 + cc;

    // LDS -> registers: 5x ds_read_b128 per series. xi reads broadcast across
    // lanes sharing i; xj rows (stride 20 floats = 80 B) hit all 32 banks
    // across j mod 8 -> at most light multi-way aliasing.
    float xi[NROW], xj[NROW], pr[NROW];
    const float4* pi4 = (const float4*)(xt + i * NROW);  // rows are 16B-aligned (80 B)
    const float4* pj4 = (const float4*)(xt + j * NROW);
    #pragma unroll
    for (int k = 0; k < NROW / 4; ++k) {
        float4 a = pi4[k], c4 = pj4[k];
        xi[4 * k + 0] = a.x;  xi[4 * k + 1] = a.y;
        xi[4 * k + 2] = a.z;  xi[4 * k + 3] = a.w;
        xj[4 * k + 0] = c4.x; xj[4 * k + 1] = c4.y;
        xj[4 * k + 2] = c4.z; xj[4 * k + 3] = c4.w;
    }
    #pragma unroll
    for (int t = 0; t < NROW; ++t) pr[t] = xi[t] * xj[t];

    float Si = (xi[0] + xi[1]) + (xi[2] + xi[3]) + xi[4];
    float Sj = (xj[0] + xj[1]) + (xj[2] + xj[3]) + xj[4];
    float P  = (pr[0] + pr[1]) + (pr[2] + pr[3]) + pr[4];

    // ---- Sliding windows, store streamed per window (coalesced 256 B/wave) ----
    float* op = out + ((size_t)b * S_DIM + s0) * C_DIM + tid;
    #pragma unroll
    for (int w = 0; w < NS; ++w) {
        float cov = 0.2f * P - (0.2f * Si) * (0.2f * Sj);
        if (w < nw) op[(size_t)w * C_DIM] = cov;
        if (w + 1 < NS) {
            Si += xi[w + WIN] - xi[w];
            Sj += xj[w + WIN] - xj[w];
            P  += pr[w + WIN] - pr[w];
        }
    }
}

extern "C" void kernel_launch(void* const* d_in, const int* in_sizes, int n_in,
                              void* d_out, int out_size, void* d_ws, size_t ws_size,
                              hipStream_t stream) {
    const float* x = (const float*)d_in[0];
    float* out     = (float*)d_out;

    dim3 grid((S_DIM + NS - 1) / NS, B_DIM);   // (32, 256)
    dim3 block(512);
    ts_cov_kernel<<<grid, block, 0, stream>>>(x, out);
}

// Round 2
// 262.123 us; speedup vs baseline: 1.0359x; 1.0359x over previous
//
#include <hip/hip_runtime.h>

// ts_cov: x[B=256, T=512, F=32] fp32 -> cov[B, S=508, C=496] fp32
// cov[b,s,c(i,j)] = mean_{t in [s,s+5)} x_i x_j - mean(x_i) mean(x_j), pairs i<j row-major.
//
// Write-BW-bound (~258 MB out; floor ~43 us at fill-demonstrated 6.1 TB/s).
// v3 = v2 + NON-TEMPORAL stores. v1 (128thr/4pair/burst) and v2 (512thr/1pair/
// streamed) measured IDENTICAL (270.5 vs 271.5 us) -> occupancy/store-shape is
// not the limiter. Remaining candidate for the kernel's write path running below
// fill BW: L2 write-allocate on store miss (the rocclr fill shows FETCH=14.5KB
// on 1.03GB written -> it avoids allocation; our dword stores may not).
// __builtin_nontemporal_store emits global_store_dword ...nt, bypassing L2
// allocation. Output is write-once/never-read, so nt is semantically ideal.
// Everything else is byte-identical to the verified v2.

#define T_DIM 512
#define F_DIM 32
#define B_DIM 256
#define WIN 5
#define S_DIM (T_DIM - WIN + 1)          // 508
#define C_DIM (F_DIM * (F_DIM - 1) / 2)  // 496
#define NS 16                            // windows per block
#define NROW (NS + WIN - 1)              // 20 x-rows staged per block

__global__ __launch_bounds__(512) void ts_cov_kernel(const float* __restrict__ x,
                                                     float* __restrict__ out) {
    __shared__ float xt[F_DIM * NROW];   // transposed: xt[f*NROW + t], 2560 B

    const int b   = blockIdx.y;
    const int s0  = blockIdx.x * NS;     // 0,16,...,496
    const int tid = threadIdx.x;

    // ---- Stage x[b, s0 : s0+NROW, :] into LDS, transposed (160 float4s) ----
    const float4* xsrc = (const float4*)(x + ((size_t)b * T_DIM + s0) * F_DIM);
    const int nrow_avail = min(NROW, T_DIM - s0);          // 20, or 16 for last tile
    if (tid < NROW * F_DIM / 4) {
        const int t  = tid >> 3;                           // row within tile
        const int f4 = tid & 7;                            // float4 within row
        float4 v = (t < nrow_avail) ? xsrc[tid] : make_float4(0.f, 0.f, 0.f, 0.f);
        xt[(4 * f4 + 0) * NROW + t] = v.x;
        xt[(4 * f4 + 1) * NROW + t] = v.y;
        xt[(4 * f4 + 2) * NROW + t] = v.z;
        xt[(4 * f4 + 3) * NROW + t] = v.w;
    }
    __syncthreads();

    if (tid >= C_DIM) return;            // 496 active lanes, one pair each

    const int nw = min(NS, S_DIM - s0);  // 16, or 12 for last tile

    // Decode pair (i, j) for c = tid. Lanes are consecutive in c, so a wave's
    // stores cover 64 consecutive floats (256 B, full 64B lines).
    int i = 0, cc = tid;
    while (cc >= F_DIM - 1 - i) { cc -= F_DIM - 1 - i; ++i; }
    const int j = i + 1 + cc;

    // LDS -> registers: 5x ds_read_b128 per series. xi reads broadcast across
    // lanes sharing i; xj rows (stride 20 floats = 80 B) hit all 32 banks
    // across j mod 8 -> at most light multi-way aliasing.
    float xi[NROW], xj[NROW], pr[NROW];
    const float4* pi4 = (const float4*)(xt + i * NROW);  // rows are 16B-aligned (80 B)
    const float4* pj4 = (const float4*)(xt + j * NROW);
    #pragma unroll
    for (int k = 0; k < NROW / 4; ++k) {
        float4 a = pi4[k], c4 = pj4[k];
        xi[4 * k + 0] = a.x;  xi[4 * k + 1] = a.y;
        xi[4 * k + 2] = a.z;  xi[4 * k + 3] = a.w;
        xj[4 * k + 0] = c4.x; xj[4 * k + 1] = c4.y;
        xj[4 * k + 2] = c4.z; xj[4 * k + 3] = c4.w;
    }
    #pragma unroll
    for (int t = 0; t < NROW; ++t) pr[t] = xi[t] * xj[t];

    float Si = (xi[0] + xi[1]) + (xi[2] + xi[3]) + xi[4];
    float Sj = (xj[0] + xj[1]) + (xj[2] + xj[3]) + xj[4];
    float P  = (pr[0] + pr[1]) + (pr[2] + pr[3]) + pr[4];

    // ---- Sliding windows; non-temporal store streamed per window ----
    float* op = out + ((size_t)b * S_DIM + s0) * C_DIM + tid;
    #pragma unroll
    for (int w = 0; w < NS; ++w) {
        float cov = 0.2f * P - (0.2f * Si) * (0.2f * Sj);
        if (w < nw) __builtin_nontemporal_store(cov, op + (size_t)w * C_DIM);
        if (w + 1 < NS) {
            Si += xi[w + WIN] - xi[w];
            Sj += xj[w + WIN] - xj[w];
            P  += pr[w + WIN] - pr[w];
        }
    }
}

extern "C" void kernel_launch(void* const* d_in, const int* in_sizes, int n_in,
                              void* d_out, int out_size, void* d_ws, size_t ws_size,
                              hipStream_t stream) {
    const float* x = (const float*)d_in[0];
    float* out     = (float*)d_out;

    dim3 grid((S_DIM + NS - 1) / NS, B_DIM);   // (32, 256)
    dim3 block(512);
    ts_cov_kernel<<<grid, block, 0, stream>>>(x, out);
}